// Round 4
// baseline (158.272 us; speedup 1.0000x reference)
//
#include <hip/hip_runtime.h>
#include <math.h>

#define NQK 16   // Q*K = 4*4

// One launch, grid 1024 = (i, j-quarter), 512 threads (8 waves).
// Block b: i = b>>2, j-range [ (b&3)*64, +64 ).
//   A1: rebuild SJ/CJ = sin/cos(C[j,q]*k) for the block's 64 j-rows.
//       thread = (j, q, half): half-row dot (256 elems) in-lane, one
//       shfl_xor(1) combine, 2 sincos per thread -> LDS.
//   A2: AP/BQ = A*cos(Bp), A*sin(Bp): 2 elems + 2 sincos per thread -> LDS.
//   A3: SI/CI = sin/cos(w[q]*t[i]*k): 16 threads, 1 sincos each -> LDS.
//   B : per-lane (o = tid&63) fold i-phase: P = AP*ci - BQ*si, Qc = AP*si + BQ*ci.
//   C : wave wv handles 8 j-rows: 8 broadcast LDS float4 reads + 32 FMA
//       per row, coalesced 4B stores (lane = o).
__global__ __launch_bounds__(512) void fused_kernel(
    const float* __restrict__ X0, const float* __restrict__ t,
    const float* __restrict__ Wc_w, const float* __restrict__ Wc_b,
    const float* __restrict__ w, const float* __restrict__ A,
    const float* __restrict__ Bp, float* __restrict__ out)
{
    __shared__ float SJ[64 * NQK];    // 4 KiB
    __shared__ float CJ[64 * NQK];    // 4 KiB
    __shared__ float APs[64 * NQK];   // 4 KiB
    __shared__ float BQs[64 * NQK];   // 4 KiB
    __shared__ float SIs[NQK], CIs[NQK];

    const int b   = blockIdx.x;
    const int i   = b >> 2;
    const int jb0 = (b & 3) * 64;
    const int tid = threadIdx.x;

    // ---- A2: weight fold (i-independent) ----
    {
        const int e0 = tid * 2;            // element pair in A/Bp (64x16)
        const float2 a2  = *(const float2*)(A  + e0);
        const float2 b2  = *(const float2*)(Bp + e0);
        float s0, c0, s1, c1;
        sincosf(b2.x, &s0, &c0);
        sincosf(b2.y, &s1, &c1);
        APs[e0]     = a2.x * c0;  BQs[e0]     = a2.x * s0;
        APs[e0 + 1] = a2.y * c1;  BQs[e0 + 1] = a2.y * s1;
    }

    // ---- A3: i-side phases ----
    if (tid < NQK) {
        const int qq = tid >> 2;
        const int kk = (tid & 3) + 1;
        float s, c;
        sincosf(w[qq] * t[i] * (float)kk, &s, &c);
        SIs[tid] = s;
        CIs[tid] = c;
    }

    // ---- A1: j-side tables for this block's 64 rows ----
    {
        const int jl = tid >> 3;           // 0..63 local j
        const int q  = (tid >> 1) & 3;     // 0..3
        const int h  = tid & 1;            // half of the 512-dot
        const float4* xr = (const float4*)(X0 + (size_t)(jb0 + jl) * 512 + h * 256);
        const float4* wr = (const float4*)(Wc_w + (size_t)q * 512 + h * 256);
        float acc = 0.f;
#pragma unroll 8
        for (int m = 0; m < 64; ++m) {
            float4 xv = xr[m], wv4 = wr[m];
            acc += xv.x * wv4.x + xv.y * wv4.y + xv.z * wv4.z + xv.w * wv4.w;
        }
        acc += __shfl_xor(acc, 1, 64);     // combine the two halves
        const float cval = acc + Wc_b[q];
        const int k0 = h * 2 + 1;          // h=0 -> k 1,2 ; h=1 -> k 3,4
        float s, c;
        sincosf(cval * (float)k0, &s, &c);
        SJ[jl * NQK + q * 4 + (k0 - 1)] = s;
        CJ[jl * NQK + q * 4 + (k0 - 1)] = c;
        sincosf(cval * (float)(k0 + 1), &s, &c);
        SJ[jl * NQK + q * 4 + k0] = s;
        CJ[jl * NQK + q * 4 + k0] = c;
    }

    __syncthreads();

    // ---- B: per-lane rank-32 weights with i-phase folded ----
    const int o = tid & 63;
    float P[NQK], Qc[NQK];
    {
        const float4* ap4 = (const float4*)(APs + o * NQK);
        const float4* bq4 = (const float4*)(BQs + o * NQK);
        const float4* si4 = (const float4*)SIs;
        const float4* ci4 = (const float4*)CIs;
#pragma unroll
        for (int m = 0; m < 4; ++m) {
            float4 va = ap4[m], vb = bq4[m], vs = si4[m], vc = ci4[m];
            P[4 * m + 0]  = va.x * vc.x - vb.x * vs.x;
            P[4 * m + 1]  = va.y * vc.y - vb.y * vs.y;
            P[4 * m + 2]  = va.z * vc.z - vb.z * vs.z;
            P[4 * m + 3]  = va.w * vc.w - vb.w * vs.w;
            Qc[4 * m + 0] = va.x * vs.x + vb.x * vc.x;
            Qc[4 * m + 1] = va.y * vs.y + vb.y * vc.y;
            Qc[4 * m + 2] = va.z * vs.z + vb.z * vc.z;
            Qc[4 * m + 3] = va.w * vs.w + vb.w * vc.w;
        }
    }

    // ---- C: contraction, wave wv -> 8 j-rows, lane = o ----
    const int wv = __builtin_amdgcn_readfirstlane(tid >> 6);
    float* outb = out + ((size_t)(i * 256 + jb0 + wv * 8)) * 64 + o;
#pragma unroll 2
    for (int jj = 0; jj < 8; ++jj) {
        const float4* sj4 = (const float4*)(SJ + (wv * 8 + jj) * NQK);
        const float4* cj4 = (const float4*)(CJ + (wv * 8 + jj) * NQK);
        float acc = 0.f;
#pragma unroll
        for (int m = 0; m < 4; ++m) {
            float4 vs = sj4[m], vc = cj4[m];
            acc += P[4 * m + 0] * vs.x + Qc[4 * m + 0] * vc.x;
            acc += P[4 * m + 1] * vs.y + Qc[4 * m + 1] * vc.y;
            acc += P[4 * m + 2] * vs.z + Qc[4 * m + 2] * vc.z;
            acc += P[4 * m + 3] * vs.w + Qc[4 * m + 3] * vc.w;
        }
        outb[jj * 64] = acc;
    }
}

extern "C" void kernel_launch(void* const* d_in, const int* in_sizes, int n_in,
                              void* d_out, int out_size, void* d_ws, size_t ws_size,
                              hipStream_t stream) {
    const float* X0   = (const float*)d_in[0];
    const float* t    = (const float*)d_in[1];
    const float* Wc_w = (const float*)d_in[2];
    const float* Wc_b = (const float*)d_in[3];
    const float* w    = (const float*)d_in[4];
    const float* A    = (const float*)d_in[5];
    const float* Bp   = (const float*)d_in[6];
    float* out = (float*)d_out;

    fused_kernel<<<dim3(1024), dim3(512), 0, stream>>>(
        X0, t, Wc_w, Wc_b, w, A, Bp, out);
}

// Round 5
// 78.818 us; speedup vs baseline: 2.0081x; 2.0081x over previous
//
#include <hip/hip_runtime.h>
#include <math.h>

#define NQK 16   // Q*K = 4*4

// ws layout (floats):
//   SJ [256*16] @ 0       sin(C[j,q]*k)
//   CJ [256*16] @ 4096    cos(C[j,q]*k)
//   SI [256*16] @ 8192    sin(w[q]*t[i]*k)
//   CI [256*16] @ 12288   cos(w[q]*t[i]*k)
//   AP [64*16]  @ 16384   A*cos(Bp)
//   BQ [64*16]  @ 17408   A*sin(Bp)
// total 18432 floats = 73728 bytes  (all L2-resident for the main kernel)

__global__ __launch_bounds__(256) void prep_kernel(
    const float* __restrict__ X0, const float* __restrict__ t,
    const float* __restrict__ Wc_w, const float* __restrict__ Wc_b,
    const float* __restrict__ w, const float* __restrict__ A,
    const float* __restrict__ Bp, float* __restrict__ ws)
{
    float* SJ = ws;
    float* CJ = ws + 4096;
    float* SI = ws + 8192;
    float* CI = ws + 12288;
    float* AP = ws + 16384;
    float* BQ = ws + 17408;

    const int j    = blockIdx.x;      // doubles as i-index and (if <64) o-index
    const int tid  = threadIdx.x;
    const int lane = tid & 63;
    const int q    = tid >> 6;        // wave id = q (4 waves)

    // ---- i-side table (i = blockIdx): SI/CI[i*16 + q*4 + (k-1)] ----
    if (tid < 16) {
        const int qq = tid >> 2;
        const int kk = (tid & 3) + 1;
        float s, c;
        sincosf(w[qq] * t[j] * (float)kk, &s, &c);
        SI[j * 16 + tid] = s;
        CI[j * 16 + tid] = c;
    }

    // ---- weight fold (o = blockIdx < 64): AP/BQ[o*16 + qk] ----
    if (j < 64 && tid >= 64 && tid < 80) {
        const int qk = tid - 64;
        float a = A[j * 16 + qk];
        float sb, cb;
        sincosf(Bp[j * 16 + qk], &sb, &cb);
        AP[j * 16 + qk] = a * cb;
        BQ[j * 16 + qk] = a * sb;
    }

    // ---- C[j][q] = dot(X0[j,:], Wc_w[q,:]) + Wc_b[q], wave q per q ----
    const float4* xr = (const float4*)(X0 + (size_t)j * 512);
    const float4* wr = (const float4*)(Wc_w + (size_t)q * 512);
    float part = 0.f;
#pragma unroll
    for (int m = 0; m < 2; ++m) {
        float4 xv = xr[lane + 64 * m];
        float4 wv4 = wr[lane + 64 * m];
        part += xv.x * wv4.x + xv.y * wv4.y + xv.z * wv4.z + xv.w * wv4.w;
    }
#pragma unroll
    for (int off = 32; off > 0; off >>= 1)
        part += __shfl_xor(part, off, 64);
    const float cval = part + Wc_b[q];

    // lanes 0..3 emit k = 1..4
    if (lane < 4) {
        float s, c;
        sincosf(cval * (float)(lane + 1), &s, &c);
        SJ[j * 16 + q * 4 + lane] = s;
        CJ[j * 16 + q * 4 + lane] = c;
    }
}

// grid 2048 x 256 threads (4 waves). block b: i = b>>3, j-seg (b&7)*32.
// wave wv handles 8 j's; lane = o (coalesced stores).
// SJ/CJ row addresses are wave-uniform -> scalar (K$) loads.
__global__ __launch_bounds__(256) void main_kernel(
    const float* __restrict__ ws, float* __restrict__ out)
{
    const float* SJ = ws;
    const float* CJ = ws + 4096;
    const float* SI = ws + 8192;
    const float* CI = ws + 12288;
    const float* AP = ws + 16384;
    const float* BQ = ws + 17408;

    const int b   = blockIdx.x;
    const int i   = b >> 3;
    const int jb0 = (b & 7) * 32;
    const int tid = threadIdx.x;
    const int o   = tid & 63;
    const int wv  = __builtin_amdgcn_readfirstlane(tid >> 6);  // SGPR wave id
    const int jbase = jb0 + wv * 8;

    // fold the block-uniform i-side phases into the per-o weights:
    // P = AP*ci - BQ*si ; Q = AP*si + BQ*ci
    float P[NQK], Qc[NQK];
    {
        const float4* a4  = (const float4*)(AP + o * NQK);
        const float4* b4  = (const float4*)(BQ + o * NQK);
        const float4* si4 = (const float4*)(SI + i * NQK);   // uniform -> s_load
        const float4* ci4 = (const float4*)(CI + i * NQK);   // uniform -> s_load
#pragma unroll
        for (int m = 0; m < 4; ++m) {
            float4 va = a4[m], vb = b4[m], vs = si4[m], vc = ci4[m];
            P[4 * m + 0]  = va.x * vc.x - vb.x * vs.x;
            P[4 * m + 1]  = va.y * vc.y - vb.y * vs.y;
            P[4 * m + 2]  = va.z * vc.z - vb.z * vs.z;
            P[4 * m + 3]  = va.w * vc.w - vb.w * vs.w;
            Qc[4 * m + 0] = va.x * vs.x + vb.x * vc.x;
            Qc[4 * m + 1] = va.y * vs.y + vb.y * vc.y;
            Qc[4 * m + 2] = va.z * vs.z + vb.z * vc.z;
            Qc[4 * m + 3] = va.w * vs.w + vb.w * vc.w;
        }
    }

    float* outb = out + ((size_t)(i * 256 + jbase)) * 64 + o;

#pragma unroll
    for (int jj = 0; jj < 8; ++jj) {
        const float4* sj4 = (const float4*)(SJ + (jbase + jj) * NQK);  // uniform
        const float4* cj4 = (const float4*)(CJ + (jbase + jj) * NQK);  // uniform
        float acc = 0.f;
#pragma unroll
        for (int m = 0; m < 4; ++m) {
            float4 vs = sj4[m], vc = cj4[m];
            acc += P[4 * m + 0] * vs.x + Qc[4 * m + 0] * vc.x;
            acc += P[4 * m + 1] * vs.y + Qc[4 * m + 1] * vc.y;
            acc += P[4 * m + 2] * vs.z + Qc[4 * m + 2] * vc.z;
            acc += P[4 * m + 3] * vs.w + Qc[4 * m + 3] * vc.w;
        }
        outb[jj * 64] = acc;
    }
}

extern "C" void kernel_launch(void* const* d_in, const int* in_sizes, int n_in,
                              void* d_out, int out_size, void* d_ws, size_t ws_size,
                              hipStream_t stream) {
    const float* X0   = (const float*)d_in[0];
    const float* t    = (const float*)d_in[1];
    const float* Wc_w = (const float*)d_in[2];
    const float* Wc_b = (const float*)d_in[3];
    const float* w    = (const float*)d_in[4];
    const float* A    = (const float*)d_in[5];
    const float* Bp   = (const float*)d_in[6];
    float* out = (float*)d_out;
    float* ws  = (float*)d_ws;

    prep_kernel<<<dim3(256), dim3(256), 0, stream>>>(X0, t, Wc_w, Wc_b, w, A, Bp, ws);
    main_kernel<<<dim3(2048), dim3(256), 0, stream>>>(ws, out);
}